// Round 4
// baseline (246.916 us; speedup 1.0000x reference)
//
#include <hip/hip_runtime.h>

typedef short short8 __attribute__((ext_vector_type(8)));
typedef float f32x4 __attribute__((ext_vector_type(4)));
typedef unsigned short u16;
typedef __attribute__((address_space(3))) unsigned lds_u32_t;
typedef __attribute__((address_space(1))) const unsigned glb_u32_t;

namespace {
constexpr int NIMG = 16;
constexpr int CIN  = 256;
constexpr int HIMG = 56;
constexpr int WIMG = 56;
constexpr int KOUT = 256;
constexpr int PIX  = HIMG * WIMG;          // 3136
constexpr int HPAD = 58;
constexpr int PP   = HPAD * HPAD;          // 3364
constexpr int TILES = 26;                  // 26*128 = 3328 >= 3246
constexpr int NX   = NIMG * CIN * PIX;     // 12,845,056
constexpr int NGX  = (NX + 35) / 36;       // 356,808
constexpr int NWEL = KOUT * CIN * 9;       // 589,824
constexpr int XQ_HALVES = NIMG * 32 * PP * 8;   // 13,778,944
constexpr int MAXB = XQ_HALVES - 8;
constexpr int NHALO = NIMG * 32 * 228;
constexpr int QBLK = 1393;                 // full 256-group blocks (1393*9216 floats)
}

// ---------------------------------------------------------------------------
// BFP quantize x (NCHW fp32) -> NCHW bf16, LDS-staged so both the global
// reads (float4, lane-contiguous) and writes (uint2, lane-contiguous) are
// perfectly coalesced. Each thread owns one 36-elem group read from LDS.
// ---------------------------------------------------------------------------
__global__ __launch_bounds__(256) void quant_x_nchw(
        const float* __restrict__ x, u16* __restrict__ qn) {
    __shared__ float sf[9216];                 // 36 KB staging
    u16* su = (u16*)sf;                        // reused for output staging
    const int b = blockIdx.x;
    const int t = threadIdx.x;
    const size_t base = (size_t)b * 9216;

    if (b < QBLK) {
        const float4* src = (const float4*)(x + base);
#pragma unroll
        for (int j = 0; j < 9; j++)
            *(float4*)&sf[4 * (t + 256 * j)] = src[t + 256 * j];
        __syncthreads();
        float v[36];
#pragma unroll
        for (int j = 0; j < 36; j++) v[j] = sf[36 * t + j];
        float ma = 0.f;
#pragma unroll
        for (int j = 0; j < 36; j++) ma = fmaxf(ma, fabsf(v[j]));
        float scale = 0.f, rinv = 0.f;
        if (ma != 0.f) {
            float e = floorf(log2f(ma));
            scale = exp2f(e - 7.f);
            rinv  = exp2f(7.f - e);
        }
        u16 qq[36];
#pragma unroll
        for (int j = 0; j < 36; j++) {
            float q = rintf(v[j] * rinv);                 // round-half-even
            q = fminf(fmaxf(q, -128.f), 127.f) * scale;
            qq[j] = (u16)(__float_as_uint(q) >> 16);      // exact bf16
        }
        __syncthreads();                                  // all LDS reads done
#pragma unroll
        for (int j = 0; j < 36; j++) su[36 * t + j] = qq[j];
        __syncthreads();
        uint2* dst = (uint2*)(qn + base);
        const uint2* s2 = (const uint2*)su;
#pragma unroll
        for (int j = 0; j < 9; j++) dst[t + 256 * j] = s2[t + 256 * j];
    } else {
        // tail: 200 groups, scalar guarded path
        int g = b * 256 + t;
        if (g >= NGX) return;
        int gb = g * 36;
        int cnt = NX - gb; if (cnt > 36) cnt = 36;
        float v[36];
        for (int j = 0; j < 36; j++) v[j] = (j < cnt) ? x[gb + j] : 0.f;
        float ma = 0.f;
        for (int j = 0; j < 36; j++) ma = fmaxf(ma, fabsf(v[j]));
        float scale = 0.f, rinv = 0.f;
        if (ma != 0.f) {
            float e = floorf(log2f(ma));
            scale = exp2f(e - 7.f);
            rinv  = exp2f(7.f - e);
        }
        for (int j = 0; j < cnt; j++) {
            float q = rintf(v[j] * rinv);
            q = fminf(fmaxf(q, -128.f), 127.f) * scale;
            qn[gb + j] = (u16)(__float_as_uint(q) >> 16);
        }
    }
}

// ---------------------------------------------------------------------------
// LDS-tiled scatter NCHW bf16 -> channel-chunked padded layout
//   xq2[n][cc=c/8][pp=ph*58+pw][8], interior only.
// ---------------------------------------------------------------------------
__global__ __launch_bounds__(256) void transpose_x(
        const u16* __restrict__ qn, u16* __restrict__ xq2) {
    __shared__ uint tile[64][65];
    const int t  = threadIdx.x;
    const int p0 = blockIdx.x * 64;
    const int c0 = blockIdx.y * 64;
    const int n  = blockIdx.z;

    const int jc  = t & 7;
    const int ci0 = t >> 3;
#pragma unroll
    for (int l = 0; l < 2; l++) {
        int ci = ci0 + 32 * l;
        const short8 vv = *(const short8*)(qn + (size_t)n * CIN * PIX
                                           + (c0 + ci) * PIX + p0 + jc * 8);
#pragma unroll
        for (int j = 0; j < 8; j++)
            tile[ci][jc * 8 + j] = (uint)(u16)vv[j];
    }
    __syncthreads();

    const int pi  = t & 63;
    const int cc0 = t >> 6;
    const int p = p0 + pi;
    const int i = p / WIMG, j = p % WIMG;
    const int pp = (i + 1) * HPAD + (j + 1);
#pragma unroll
    for (int s = 0; s < 2; s++) {
        int cc = cc0 + 4 * s;
        short8 o;
#pragma unroll
        for (int q = 0; q < 8; q++)
            o[q] = (short)tile[cc * 8 + q][pi];
        *(short8*)(xq2 + ((size_t)(n * 32 + (c0 >> 3) + cc) * PP + pp) * 8) = o;
    }
}

// ---------------------------------------------------------------------------
// Fused: quantize weights -> wt2[rs][cs][kc][kout][8]; zero halo of xq2.
// ---------------------------------------------------------------------------
__global__ void quant_w_halo(const float* __restrict__ wsrc,
                             u16* __restrict__ wt2, u16* __restrict__ xq2) {
    int b = blockIdx.x;
    if (b < 64) {
        int g = b * 256 + threadIdx.x;
        int base = g * 36;
        float v[36];
        const float4* p4 = (const float4*)(wsrc + base);
#pragma unroll
        for (int j = 0; j < 9; j++) {
            float4 t = p4[j];
            v[4*j+0] = t.x; v[4*j+1] = t.y; v[4*j+2] = t.z; v[4*j+3] = t.w;
        }
        float ma = 0.f;
#pragma unroll
        for (int j = 0; j < 36; j++) ma = fmaxf(ma, fabsf(v[j]));
        float scale = 0.f, rinv = 0.f;
        if (ma != 0.f) {
            float e = floorf(log2f(ma));
            scale = exp2f(e - 7.f);
            rinv  = exp2f(7.f - e);
        }
        int k  = g >> 6;
        int c0 = (g & 63) * 4;
#pragma unroll
        for (int j = 0; j < 36; j++) {
            float q = rintf(v[j] * rinv);
            q = fminf(fmaxf(q, -128.f), 127.f) * scale;
            int c  = c0 + j / 9;
            int rs = j % 9;
            int idx = ((((rs * 8 + (c >> 5)) * 4 + ((c >> 3) & 3)) * KOUT) + k) * 8 + (c & 7);
            wt2[idx] = (u16)(__float_as_uint(q) >> 16);
        }
    } else {
        int t = (b - 64) * 256 + threadIdx.x;
        if (t >= NHALO) return;
        int s   = t % 228;
        int ccn = t / 228;
        int cc = ccn & 31, n = ccn >> 5;
        int ph, pw;
        if (s < 58)       { ph = 0;  pw = s; }
        else if (s < 116) { ph = 57; pw = s - 58; }
        else { int r = s - 116; ph = 1 + (r >> 1); pw = (r & 1) * 57; }
        *(uint4*)(xq2 + ((size_t)(n * 32 + cc) * PP + ph * HPAD + pw) * 8) =
            make_uint4(0, 0, 0, 0);
    }
}

// ---------------------------------------------------------------------------
// Implicit-GEMM conv, single-barrier double-buffered pipeline:
//   prefetch(s+1) -> alt buffers (async global_load_lds), compute(s),
//   barrier (drains the prefetch, which had the whole compute phase in
//   flight). 72 stages = 8 cs x 9 taps.
// ---------------------------------------------------------------------------
__global__ __launch_bounds__(256) void conv_kernel(
        const u16* __restrict__ xq2, const u16* __restrict__ wt2,
        const float* __restrict__ bias, float* __restrict__ out) {
    __shared__ u16 lA[2][4096];   // [buf][kc(4)][kout row(128)][8]
    __shared__ u16 lB[2][4096];   // [buf][kc(4)][col(128)][8]

    const int tid  = threadIdx.x;
    const int lane = tid & 63;
    const int wv   = tid >> 6;
    const int bx   = blockIdx.x;
    const int n    = bx / TILES;
    const int t0   = (bx % TILES) * 128;
    const int k0   = blockIdx.y * 128;

    const int aLane = (wv * KOUT + k0 + lane) * 8;
    const int bLane = ((n * 32 + wv) * PP + t0 + lane) * 8;

    const int frow = lane & 15;
    const int fkk  = lane >> 4;
    const int fAo = fkk * 1024 + ((wv >> 1) * 64 + frow) * 8;
    const int fBo = fkk * 1024 + ((wv & 1) * 64 + frow) * 8;

    f32x4 acc[4][4] = {};

    auto prefetch = [&](int s, int p) {
        int cs = s / 9, rs = s - cs * 9;
        int xoff = (rs / 3) * HPAD + (rs % 3);
        int aIdx = aLane + (rs * 8 + cs) * 8192;
        int bI0  = bLane + cs * 107648 + xoff * 8;
#pragma unroll
        for (int i = 0; i < 2; i++)
            __builtin_amdgcn_global_load_lds(
                (glb_u32_t*)(wt2 + aIdx + i * 512),
                (lds_u32_t*)(&lA[p][wv * 1024 + i * 512]), 16, 0, 0);
#pragma unroll
        for (int i = 0; i < 2; i++) {
            int idx = bI0 + i * 512;
            idx = min(idx, MAXB);
            __builtin_amdgcn_global_load_lds(
                (glb_u32_t*)(xq2 + idx),
                (lds_u32_t*)(&lB[p][wv * 1024 + i * 512]), 16, 0, 0);
        }
    };

    prefetch(0, 0);
    __syncthreads();                  // drain stage-0 loads

    for (int s = 0; s < 72; s++) {
        const int p = s & 1;
        if (s < 71) prefetch(s + 1, p ^ 1);   // async into alt buffers
        const u16* fA = &lA[p][0] + fAo;
        const u16* fB = &lB[p][0] + fBo;
        short8 af[4], bf[4];
#pragma unroll
        for (int i = 0; i < 4; i++) af[i] = *(const short8*)(fA + i * 128);
#pragma unroll
        for (int j = 0; j < 4; j++) bf[j] = *(const short8*)(fB + j * 128);
#pragma unroll
        for (int i = 0; i < 4; i++)
#pragma unroll
            for (int j = 0; j < 4; j++)
                acc[i][j] = __builtin_amdgcn_mfma_f32_16x16x32_bf16(
                    af[i], bf[j], acc[i][j], 0, 0, 0);
        __syncthreads();              // readers done with buf p; prefetch drained
    }

    const int kbase = k0 + (wv >> 1) * 64 + fkk * 4;
    const int mbase = (wv & 1) * 64 + frow;
#pragma unroll
    for (int j = 0; j < 4; j++) {
        int ppp = t0 + mbase + j * 16;
        int h = ppp / HPAD, w = ppp % HPAD;
        if (w < WIMG && h < HIMG) {
            float* ob = out + (size_t)n * KOUT * PIX + h * WIMG + w;
#pragma unroll
            for (int i = 0; i < 4; i++) {
                int kch = kbase + i * 16;
#pragma unroll
                for (int r = 0; r < 4; r++)
                    ob[(size_t)(kch + r) * PIX] = acc[i][j][r] + bias[kch + r];
            }
        }
    }
}

// ---------------------------------------------------------------------------
extern "C" void kernel_launch(void* const* d_in, const int* in_sizes, int n_in,
                              void* d_out, int out_size, void* d_ws, size_t ws_size,
                              hipStream_t stream) {
    const float* x   = (const float*)d_in[0];
    const float* wgt = (const float*)d_in[1];
    const float* bs  = (const float*)d_in[2];
    float* out = (float*)d_out;

    u16* xq2 = (u16*)d_ws;                 // 27.56 MB chunked padded activations
    u16* wt2 = xq2 + XQ_HALVES;            // 1.18 MB  staged weight layout
    u16* qn  = wt2 + NWEL;                 // 25.69 MB NCHW bf16 intermediate

    quant_x_nchw<<<QBLK + 1, 256, 0, stream>>>(x, qn);
    quant_w_halo<<<64 + (NHALO + 255) / 256, 256, 0, stream>>>(wgt, wt2, xq2);
    transpose_x<<<dim3(PIX / 64, CIN / 64, NIMG), 256, 0, stream>>>(qn, xq2);
    conv_kernel<<<dim3(NIMG * TILES, 2), 256, 0, stream>>>(xq2, wt2, bs, out);
}

// Round 5
// 205.489 us; speedup vs baseline: 1.2016x; 1.2016x over previous
//
#include <hip/hip_runtime.h>

typedef short short8 __attribute__((ext_vector_type(8)));
typedef float f32x4 __attribute__((ext_vector_type(4)));
typedef unsigned short u16;
typedef __attribute__((address_space(3))) unsigned lds_u32_t;
typedef __attribute__((address_space(1))) const unsigned glb_u32_t;

namespace {
constexpr int NIMG = 16;
constexpr int CIN  = 256;
constexpr int HIMG = 56;
constexpr int WIMG = 56;
constexpr int KOUT = 256;
constexpr int PIX  = HIMG * WIMG;          // 3136
constexpr int HPAD = 58;
constexpr int PP   = HPAD * HPAD;          // 3364
constexpr int TILES = 26;                  // 26*128 = 3328 >= 3246
constexpr int NX   = NIMG * CIN * PIX;     // 12,845,056
constexpr int NGX  = (NX + 35) / 36;       // 356,808
constexpr int NWEL = KOUT * CIN * 9;       // 589,824
constexpr int XQ_HALVES = NIMG * 32 * PP * 8;   // 13,778,944
constexpr int MAXB = XQ_HALVES - 8;
constexpr int NHALO = NIMG * 32 * 228;     // 116,736
constexpr int QBLK = 1393;                 // full x-quant blocks
constexpr int XB   = QBLK + 1;             // 1394 (incl. tail block)
constexpr int WB   = 64;                   // weight-quant blocks
constexpr int HB   = (NHALO + 255) / 256;  // 456 halo blocks
}

// ---------------------------------------------------------------------------
// Fused quant kernel, dispatched by block range:
//   [0, XB)          : BFP quantize x (NCHW fp32) -> NCHW bf16, LDS-staged
//   [XB, XB+WB)      : BFP quantize weights -> wt3[rs][csp][kc][kout][8]
//   [XB+WB, ...)     : zero halo ring of xq2 (chunked padded layout)
// ---------------------------------------------------------------------------
__global__ __launch_bounds__(256) void quant_fused(
        const float* __restrict__ x, u16* __restrict__ qn,
        const float* __restrict__ wsrc, u16* __restrict__ wt3,
        u16* __restrict__ xq2) {
    __shared__ float sf[9216];                 // 36 KB staging (x path only)
    const int b = blockIdx.x;
    const int t = threadIdx.x;

    if (b < QBLK) {
        u16* su = (u16*)sf;
        const size_t base = (size_t)b * 9216;
        const float4* src = (const float4*)(x + base);
#pragma unroll
        for (int j = 0; j < 9; j++)
            *(float4*)&sf[4 * (t + 256 * j)] = src[t + 256 * j];
        __syncthreads();
        float v[36];
#pragma unroll
        for (int j = 0; j < 36; j++) v[j] = sf[36 * t + j];
        float ma = 0.f;
#pragma unroll
        for (int j = 0; j < 36; j++) ma = fmaxf(ma, fabsf(v[j]));
        float scale = 0.f, rinv = 0.f;
        if (ma != 0.f) {
            float e = floorf(log2f(ma));
            scale = exp2f(e - 7.f);
            rinv  = exp2f(7.f - e);
        }
        u16 qq[36];
#pragma unroll
        for (int j = 0; j < 36; j++) {
            float q = rintf(v[j] * rinv);                 // round-half-even
            q = fminf(fmaxf(q, -128.f), 127.f) * scale;
            qq[j] = (u16)(__float_as_uint(q) >> 16);      // exact bf16
        }
        __syncthreads();
#pragma unroll
        for (int j = 0; j < 36; j++) su[36 * t + j] = qq[j];
        __syncthreads();
        uint2* dst = (uint2*)(qn + base);
        const uint2* s2 = (const uint2*)su;
#pragma unroll
        for (int j = 0; j < 9; j++) dst[t + 256 * j] = s2[t + 256 * j];
    } else if (b == QBLK) {
        int g = b * 256 + t;
        if (g >= NGX) return;
        int gb = g * 36;
        int cnt = NX - gb; if (cnt > 36) cnt = 36;
        float v[36];
        for (int j = 0; j < 36; j++) v[j] = (j < cnt) ? x[gb + j] : 0.f;
        float ma = 0.f;
        for (int j = 0; j < 36; j++) ma = fmaxf(ma, fabsf(v[j]));
        float scale = 0.f, rinv = 0.f;
        if (ma != 0.f) {
            float e = floorf(log2f(ma));
            scale = exp2f(e - 7.f);
            rinv  = exp2f(7.f - e);
        }
        for (int j = 0; j < cnt; j++) {
            float q = rintf(v[j] * rinv);
            q = fminf(fmaxf(q, -128.f), 127.f) * scale;
            qn[gb + j] = (u16)(__float_as_uint(q) >> 16);
        }
    } else if (b < XB + WB) {
        int g = (b - XB) * 256 + t;               // < 16384
        int base = g * 36;
        float v[36];
        const float4* p4 = (const float4*)(wsrc + base);
#pragma unroll
        for (int j = 0; j < 9; j++) {
            float4 tt = p4[j];
            v[4*j+0] = tt.x; v[4*j+1] = tt.y; v[4*j+2] = tt.z; v[4*j+3] = tt.w;
        }
        float ma = 0.f;
#pragma unroll
        for (int j = 0; j < 36; j++) ma = fmaxf(ma, fabsf(v[j]));
        float scale = 0.f, rinv = 0.f;
        if (ma != 0.f) {
            float e = floorf(log2f(ma));
            scale = exp2f(e - 7.f);
            rinv  = exp2f(7.f - e);
        }
        int k  = g >> 6;
        int c0 = (g & 63) * 4;
#pragma unroll
        for (int j = 0; j < 36; j++) {
            float q = rintf(v[j] * rinv);
            q = fminf(fmaxf(q, -128.f), 127.f) * scale;
            int c  = c0 + j / 9;
            int rs = j % 9;
            // wt3[rs][c>>6][(c>>3)&7][k][c&7]
            int idx = ((((rs * 4 + (c >> 6)) * 8 + ((c >> 3) & 7)) * KOUT) + k) * 8 + (c & 7);
            wt3[idx] = (u16)(__float_as_uint(q) >> 16);
        }
    } else {
        int tt = (b - XB - WB) * 256 + t;
        if (tt >= NHALO) return;
        int s   = tt % 228;
        int ccn = tt / 228;
        int cc = ccn & 31, n = ccn >> 5;
        int ph, pw;
        if (s < 58)       { ph = 0;  pw = s; }
        else if (s < 116) { ph = 57; pw = s - 58; }
        else { int r = s - 116; ph = 1 + (r >> 1); pw = (r & 1) * 57; }
        *(uint4*)(xq2 + ((size_t)(n * 32 + cc) * PP + ph * HPAD + pw) * 8) =
            make_uint4(0, 0, 0, 0);
    }
}

// ---------------------------------------------------------------------------
// LDS-tiled scatter NCHW bf16 -> channel-chunked padded layout
//   xq2[n][cc=c/8][pp=ph*58+pw][8], interior only.
// ---------------------------------------------------------------------------
__global__ __launch_bounds__(256) void transpose_x(
        const u16* __restrict__ qn, u16* __restrict__ xq2) {
    __shared__ uint tile[64][65];
    const int t  = threadIdx.x;
    const int p0 = blockIdx.x * 64;
    const int c0 = blockIdx.y * 64;
    const int n  = blockIdx.z;

    const int jc  = t & 7;
    const int ci0 = t >> 3;
#pragma unroll
    for (int l = 0; l < 2; l++) {
        int ci = ci0 + 32 * l;
        const short8 vv = *(const short8*)(qn + (size_t)n * CIN * PIX
                                           + (c0 + ci) * PIX + p0 + jc * 8);
#pragma unroll
        for (int j = 0; j < 8; j++)
            tile[ci][jc * 8 + j] = (uint)(u16)vv[j];
    }
    __syncthreads();

    const int pi  = t & 63;
    const int cc0 = t >> 6;
    const int p = p0 + pi;
    const int i = p / WIMG, j = p % WIMG;
    const int pp = (i + 1) * HPAD + (j + 1);
#pragma unroll
    for (int s = 0; s < 2; s++) {
        int cc = cc0 + 4 * s;
        short8 o;
#pragma unroll
        for (int q = 0; q < 8; q++)
            o[q] = (short)tile[cc * 8 + q][pi];
        *(short8*)(xq2 + ((size_t)(n * 32 + (c0 >> 3) + cc) * PP + pp) * 8) = o;
    }
}

// ---------------------------------------------------------------------------
// Implicit-GEMM conv, R3 2-barrier structure widened to BK=64:
// 36 stages (4 csp-slabs x 9 taps), per stage per wave: 8 async
// global_load_lds (lane-contiguous 1024B), 16 ds_read_b128, 32 MFMA.
// LDS 32 KB; occupancy grid-limited (832 blocks / 256 CU), so no loss.
// All offsets compile-time via full unroll.
// ---------------------------------------------------------------------------
__global__ __launch_bounds__(256) void conv_kernel(
        const u16* __restrict__ xq2, const u16* __restrict__ wt3,
        const float* __restrict__ bias, float* __restrict__ out) {
    __shared__ u16 lA[8192];   // [kc(8)][row(128)][8]  = 16 KB
    __shared__ u16 lB[8192];   // [kc(8)][col(128)][8]  = 16 KB

    const int tid  = threadIdx.x;
    const int lane = tid & 63;
    const int wv   = tid >> 6;
    const int bx   = blockIdx.x;
    const int n    = bx / TILES;
    const int t0   = (bx % TILES) * 128;
    const int k0   = blockIdx.y * 128;

    // global bases (u16 half-index); lane stride 8 halves = 16 B
    const int aL = (k0 + lane) * 8 + wv * 4096;            // + stage/kl/hl consts
    const int bB = ((n * 32 + 2 * wv) * PP + t0 + lane) * 8;

    const int frow = lane & 15;
    const int fkk  = lane >> 4;
    const int fAo = (fkk * 128 + (wv >> 1) * 64 + frow) * 8;
    const int fBo = (fkk * 128 + (wv & 1) * 64 + frow) * 8;

    f32x4 acc[4][4] = {};

#pragma unroll
    for (int csp = 0; csp < 4; csp++) {
#pragma unroll
        for (int rs = 0; rs < 9; rs++) {
            const int xoff8 = ((rs / 3) * HPAD + (rs % 3)) * 8;
            const int sA = (rs * 4 + csp) * 16384;     // *8*256*8 halves
            const int sB = csp * 8 * PP * 8;
            __syncthreads();                  // prev stage frag reads done
#pragma unroll
            for (int kl = 0; kl < 2; kl++)
#pragma unroll
            for (int hl = 0; hl < 2; hl++) {
                __builtin_amdgcn_global_load_lds(
                    (glb_u32_t*)(wt3 + sA + kl * 2048 + hl * 512 + aL),
                    (lds_u32_t*)(lA + wv * 2048 + kl * 1024 + hl * 512 + lane * 8),
                    16, 0, 0);
                int bi = bB + sB + kl * (PP * 8) + xoff8 + hl * 512;
                bi = min(bi, MAXB);           // only invalid-col tail lanes clamp
                __builtin_amdgcn_global_load_lds(
                    (glb_u32_t*)(xq2 + bi),
                    (lds_u32_t*)(lB + wv * 2048 + kl * 1024 + hl * 512 + lane * 8),
                    16, 0, 0);
            }
            __syncthreads();                  // vmcnt drained at barrier
#pragma unroll
            for (int ks = 0; ks < 2; ks++) {
                short8 af[4], bf[4];
#pragma unroll
                for (int i = 0; i < 4; i++)
                    af[i] = *(const short8*)(lA + ks * 4096 + fAo + i * 128);
#pragma unroll
                for (int j = 0; j < 4; j++)
                    bf[j] = *(const short8*)(lB + ks * 4096 + fBo + j * 128);
#pragma unroll
                for (int i = 0; i < 4; i++)
#pragma unroll
                    for (int j = 0; j < 4; j++)
                        acc[i][j] = __builtin_amdgcn_mfma_f32_16x16x32_bf16(
                            af[i], bf[j], acc[i][j], 0, 0, 0);
            }
        }
    }

    // epilogue: rows = outch, cols = padded pixel t0+col; skip invalid cols
    const int kbase = k0 + (wv >> 1) * 64 + fkk * 4;
    const int mbase = (wv & 1) * 64 + frow;
#pragma unroll
    for (int j = 0; j < 4; j++) {
        int ppp = t0 + mbase + j * 16;
        int h = ppp / HPAD, w = ppp % HPAD;
        if (w < WIMG && h < HIMG) {
            float* ob = out + (size_t)n * KOUT * PIX + h * WIMG + w;
#pragma unroll
            for (int i = 0; i < 4; i++) {
                int kch = kbase + i * 16;
#pragma unroll
                for (int r = 0; r < 4; r++)
                    ob[(size_t)(kch + r) * PIX] = acc[i][j][r] + bias[kch + r];
            }
        }
    }
}

// ---------------------------------------------------------------------------
extern "C" void kernel_launch(void* const* d_in, const int* in_sizes, int n_in,
                              void* d_out, int out_size, void* d_ws, size_t ws_size,
                              hipStream_t stream) {
    const float* x   = (const float*)d_in[0];
    const float* wgt = (const float*)d_in[1];
    const float* bs  = (const float*)d_in[2];
    float* out = (float*)d_out;

    u16* xq2 = (u16*)d_ws;                 // 27.56 MB chunked padded activations
    u16* wt3 = xq2 + XQ_HALVES;            // 1.18 MB  staged weight layout
    u16* qn  = wt3 + NWEL;                 // 25.69 MB NCHW bf16 intermediate

    quant_fused<<<XB + WB + HB, 256, 0, stream>>>(x, qn, wgt, wt3, xq2);
    transpose_x<<<dim3(PIX / 64, CIN / 64, NIMG), 256, 0, stream>>>(qn, xq2);
    conv_kernel<<<dim3(NIMG * TILES, 2), 256, 0, stream>>>(xq2, wt3, bs, out);
}